// Round 3
// baseline (177.523 us; speedup 1.0000x reference)
//
#include <hip/hip_runtime.h>
#include <hip/hip_bf16.h>
#include <stdint.h>

#define BB 2
#define SS 4096
#define EE 640
#define HH 4
#define DD 256
#define WIN 512

typedef __attribute__((ext_vector_type(8))) short bv8;   // 8 bf16 (4 VGPR)
typedef __attribute__((ext_vector_type(4))) float fv4;

__device__ __forceinline__ unsigned short f2b(float f) {
  union { float f; unsigned u; } a; a.f = f;
  unsigned r = a.u + 0x7fffu + ((a.u >> 16) & 1u);   // RNE
  return (unsigned short)(r >> 16);
}
__device__ __forceinline__ float b2f(unsigned short s) {
  union { unsigned u; float f; } a; a.u = ((unsigned)s) << 16;
  return a.f;
}

typedef const __attribute__((address_space(1))) unsigned int* as1u;
typedef __attribute__((address_space(3))) unsigned int* as3u;
__device__ __forceinline__ void gld16(const unsigned short* g, unsigned short* l) {
  // async global->LDS, 16B/lane; LDS dst = wave-uniform base + lane*16
  __builtin_amdgcn_global_load_lds((as1u)(const void*)g, (as3u)(void*)l, 16, 0, 0);
}

// ---------------- f32 -> bf16 cast (x) ----------------
__global__ __launch_bounds__(256) void k_cast_bf16(const float* __restrict__ src,
                                                   unsigned short* __restrict__ dst, int n4) {
  int i = blockIdx.x * 256 + threadIdx.x;
  if (i >= n4) return;
  fv4 v = ((const fv4*)src)[i];
  ushort4 o; o.x = f2b(v.x); o.y = f2b(v.y); o.z = f2b(v.z); o.w = f2b(v.w);
  ((ushort4*)dst)[i] = o;
}

// ---------------- tiled transpose + cast to bf16 ----------------
template <typename T>
__global__ __launch_bounds__(256) void k_transpose_bf16(const T* __restrict__ src,
    unsigned short* __restrict__ dst, int sstride, int dstride) {
  __shared__ float tile[32][33];
  int r0 = blockIdx.x * 32, c0 = blockIdx.y * 32;
  int t = threadIdx.x;
  int rr = t >> 3, cc = (t & 7) * 4;
  const T* p = src + (size_t)(r0 + rr) * sstride + c0 + cc;
  float v[4];
  if constexpr (sizeof(T) == 4) {
    fv4 x = *(const fv4*)p;
    v[0] = x.x; v[1] = x.y; v[2] = x.z; v[3] = x.w;
  } else {
    ushort4 x = *(const ushort4*)p;
    v[0] = b2f(x.x); v[1] = b2f(x.y); v[2] = b2f(x.z); v[3] = b2f(x.w);
  }
#pragma unroll
  for (int i = 0; i < 4; ++i) tile[cc + i][rr] = v[i];
  __syncthreads();
  ushort4 o;
  o.x = f2b(tile[rr][cc + 0]); o.y = f2b(tile[rr][cc + 1]);
  o.z = f2b(tile[rr][cc + 2]); o.w = f2b(tile[rr][cc + 3]);
  *(ushort4*)(dst + (size_t)(c0 + rr) * dstride + r0 + cc) = o;
}

// ---------------- bf16 GEMM (m97 structure): C(MxN) = A(MxK) * Bt(NxK)^T ----
// 128xBN tile, BK=32, linear LDS (64B rows, conflict-free b128),
// global_load_lds width-16 staging, XCD-chunked 1-D grid swizzle.
template <bool OUT_BF16, int BN>
__global__ __launch_bounds__(256) void k_gemm(const unsigned short* __restrict__ A,
    const unsigned short* __restrict__ Bt, void* __restrict__ Cp,
    int M, int N, int K, int nt_n) {
  __shared__ unsigned short la[128 * 32];
  __shared__ unsigned short lb[BN * 32];
  // XCD-chunk swizzle: each XCD gets a contiguous chunk of m-tiles (A-panel L2 reuse)
  const int bid = blockIdx.x;
  const int gidx = (bid & 7) * (gridDim.x >> 3) + (bid >> 3);
  const int m0 = (gidx / nt_n) * 128, n0 = (gidx % nt_n) * BN;
  const int tid = threadIdx.x, lane = tid & 63, wave = tid >> 6;
  const int g = lane >> 4, lr = lane & 15;
  constexpr int MI = (BN == 128) ? 4 : 2;   // m-frags per wave
  const int wm = (BN == 128) ? (wave >> 1) * 64 : wave * 32;
  const int wn = (BN == 128) ? (wave & 1) * 64 : 0;
  fv4 acc[MI][4] = {};
  const int srow = wave * 32 + (lane >> 2);   // A staging rows (2 calls of 16)
  const int sch = (lane & 3) * 8;
  const unsigned short* ga0 = A + (size_t)(m0 + srow) * K + sch;
  unsigned short* lad = la + wave * 1024;
  const int srowb = (BN == 128) ? srow : (wave * 16 + (lane >> 2));
  const unsigned short* gb0 = Bt + (size_t)(n0 + srowb) * K + sch;
  unsigned short* lbd = lb + ((BN == 128) ? wave * 1024 : wave * 512);
  for (int k0 = 0; k0 < K; k0 += 32) {
    __syncthreads();                        // prior tile's ds_reads done
    gld16(ga0 + k0, lad);
    gld16(ga0 + (size_t)16 * K + k0, lad + 512);
    gld16(gb0 + k0, lbd);
    if constexpr (BN == 128) gld16(gb0 + (size_t)16 * K + k0, lbd + 512);
    __syncthreads();                        // vmcnt(0) drain + barrier
    bv8 af[MI], bf[4];
#pragma unroll
    for (int mi = 0; mi < MI; ++mi) af[mi] = *(const bv8*)(la + (wm + mi * 16 + lr) * 32 + g * 8);
#pragma unroll
    for (int ni = 0; ni < 4; ++ni) bf[ni] = *(const bv8*)(lb + (wn + ni * 16 + lr) * 32 + g * 8);
    __builtin_amdgcn_s_setprio(1);
#pragma unroll
    for (int mi = 0; mi < MI; ++mi)
#pragma unroll
      for (int ni = 0; ni < 4; ++ni)
        acc[mi][ni] = __builtin_amdgcn_mfma_f32_16x16x32_bf16(af[mi], bf[ni], acc[mi][ni], 0, 0, 0);
    __builtin_amdgcn_s_setprio(0);
  }
#pragma unroll
  for (int mi = 0; mi < MI; ++mi) {
#pragma unroll
    for (int r = 0; r < 4; ++r) {
      size_t row = (size_t)(m0 + wm + mi * 16 + g * 4 + r);
#pragma unroll
      for (int ni = 0; ni < 4; ++ni) {
        int col = n0 + wn + ni * 16 + lr;
        float val = acc[mi][ni][r];
        if constexpr (OUT_BF16)
          ((unsigned short*)Cp)[row * N + col] = f2b(val);
        else
          ((float*)Cp)[row * N + col] = val;
      }
    }
  }
}

// ---------------- rmsnorm + rope (+ SCALING folded into q), bf16 out --------
__global__ __launch_bounds__(320) void k_normrope(const unsigned short* __restrict__ qkv,
    const float* __restrict__ cosp, const float* __restrict__ sinp,
    const float* __restrict__ qsc, const float* __restrict__ ksc,
    unsigned short* __restrict__ qo, unsigned short* __restrict__ ko) {
  int m = blockIdx.x;
  int b = m >> 12, s = m & 4095;
  int wave = threadIdx.x >> 6, lane = threadIdx.x & 63;
  bool isq = wave < 4;
  const unsigned short* src = qkv + (size_t)m * 1536 + (isq ? wave * 256 : 1024);
  const float* scp = isq ? qsc : ksc;
  int d0 = lane * 4;
  ushort4 raw = *(const ushort4*)(src + d0);
  float x0 = b2f(raw.x), x1 = b2f(raw.y), x2 = b2f(raw.z), x3 = b2f(raw.w);
  float ss = x0 * x0 + x1 * x1 + x2 * x2 + x3 * x3;
#pragma unroll
  for (int off = 1; off < 64; off <<= 1) ss += __shfl_xor(ss, off, 64);
  float rs = rsqrtf(ss * (1.0f / 256.0f) + 1e-6f);
  fv4 sc = *(const fv4*)(scp + d0);
  float n0 = x0 * rs * (1.0f + sc.x);
  float n1 = x1 * rs * (1.0f + sc.y);
  float n2 = x2 * rs * (1.0f + sc.z);
  float n3 = x3 * rs * (1.0f + sc.w);
  float p0 = __shfl_xor(n0, 32, 64);
  float p1 = __shfl_xor(n1, 32, 64);
  float p2 = __shfl_xor(n2, 32, 64);
  float p3 = __shfl_xor(n3, 32, 64);
  float sgn = (lane < 32) ? -1.0f : 1.0f;
  fv4 c4 = *(const fv4*)(cosp + (size_t)s * 256 + d0);
  fv4 s4 = *(const fv4*)(sinp + (size_t)s * 256 + d0);
  float mult = isq ? 0.0625f : 1.0f;
  float o0 = (n0 * c4.x + sgn * p0 * s4.x) * mult;
  float o1 = (n1 * c4.y + sgn * p1 * s4.y) * mult;
  float o2 = (n2 * c4.z + sgn * p2 * s4.z) * mult;
  float o3 = (n3 * c4.w + sgn * p3 * s4.w) * mult;
  ushort4 o; o.x = f2b(o0); o.y = f2b(o1); o.z = f2b(o2); o.w = f2b(o3);
  unsigned short* dst = isq
      ? qo + ((size_t)(b * HH + wave) * SS + s) * 256 + d0
      : ko + ((size_t)b * SS + s) * 256 + d0;
  *(ushort4*)dst = o;
}

// ---------------- flash attention, sliding window 512 ----------------------
// 64 q-rows/block, 4 waves x 16 rows, K-tile 64, fixed-max softmax.
// K: double-buffered LDS via global_load_lds, pre-swizzled source + XOR read
// (rule #21 both-sides swizzle). V: read straight from L2 (vt is [D][S];
// XCD-planar grid swizzle pins each (h,b) plane to one XCD -> K+V = 4MB fit L2).
__global__ __launch_bounds__(256) void k_attn(const unsigned short* __restrict__ q,
    const unsigned short* __restrict__ kg, const unsigned short* __restrict__ vtg,
    unsigned short* __restrict__ att) {
  __shared__ unsigned short kt[2][64 * 256]; // linear, swizzled content (64 KB)
  __shared__ unsigned short pl[4][16 * 72];  // per-wave P [qrow][key] (9 KB)
  const int plane = blockIdx.x & 7;          // XCD id == (h,b) plane
  const int h = plane & 3, b = plane >> 2;
  const int i0 = (blockIdx.x >> 3) * 64;
  const int tid = threadIdx.x, wave = tid >> 6, lane = tid & 63;
  const int g = lane >> 4, lr = lane & 15;
  const unsigned short* qp = q + ((size_t)(b * HH + h) * SS + i0 + wave * 16 + lr) * 256;
  bv8 qf[8];
#pragma unroll
  for (int kk = 0; kk < 8; ++kk) qf[kk] = *(const bv8*)(qp + kk * 32 + g * 8);
  fv4 po[16] = {};
  float lsp[4] = {0.f, 0.f, 0.f, 0.f};
  const int t0 = (i0 >= WIN) ? ((i0 - WIN + 1) >> 6) : 0;
  const int t1 = i0 >> 6;
  const unsigned short* kb = kg + (size_t)b * SS * 256;
  const unsigned short* vb = vtg + (size_t)b * 256 * SS;
  // stage K tile t into buffer p: 8 gld16 calls/wave, 2 rows (512B) per call.
  // LDS slot (row, chunk) receives global chunk^(row&7)  [16B chunks]
#define STAGEK(t, p)                                                          \
  {                                                                           \
    const unsigned short* kbase = kb + (size_t)(t) * 64 * 256;                \
    _Pragma("unroll")                                                         \
    for (int c = 0; c < 8; ++c) {                                             \
      int row_ = wave * 16 + c * 2 + (lane >> 5);                             \
      int sch_ = ((lane & 31) ^ (row_ & 7)) * 8;                              \
      gld16(kbase + (size_t)row_ * 256 + sch_, &kt[p][(wave * 16 + c * 2) * 256]); \
    }                                                                         \
  }
  STAGEK(t0, 0);
  int p = 0;
  for (int t = t0; t <= t1; ++t) {
    __syncthreads();            // drains own gld_lds (vmcnt 0) for tile t
    if (t < t1) STAGEK(t + 1, p ^ 1);   // async prefetch into other buffer
    const int jb = t * 64;
    fv4 sa[4] = {};
    __builtin_amdgcn_s_setprio(1);
#pragma unroll
    for (int n2 = 0; n2 < 4; ++n2) {
      const int row_ = n2 * 16 + lr;
#pragma unroll
      for (int kk = 0; kk < 8; ++kk) {
        bv8 kf = *(const bv8*)(&kt[p][row_ * 256 + (((kk * 4 + g) ^ (row_ & 7)) * 8)]);
        sa[n2] = __builtin_amdgcn_mfma_f32_16x16x32_bf16(qf[kk], kf, sa[n2], 0, 0, 0);
      }
    }
    __builtin_amdgcn_s_setprio(0);
    const bool need_mask = (jb + 63 > i0) || (i0 + 63 - jb >= WIN);
    if (need_mask) {
#pragma unroll
      for (int n2 = 0; n2 < 4; ++n2) {
        int j = jb + n2 * 16 + lr;
#pragma unroll
        for (int r = 0; r < 4; ++r) {
          int row = i0 + wave * 16 + g * 4 + r;
          if (j > row || row - j >= WIN) sa[n2][r] = -1e30f;
        }
      }
    }
#pragma unroll
    for (int n2 = 0; n2 < 4; ++n2)
#pragma unroll
      for (int r = 0; r < 4; ++r) {
        float pe = __expf(sa[n2][r] - 16.5f);   // scores bounded by 16 (norm=16)
        lsp[r] += pe;
        pl[wave][(g * 4 + r) * 72 + n2 * 16 + lr] = f2b(pe);
      }
    bv8 pf0 = *(const bv8*)(&pl[wave][lr * 72 + g * 8]);
    bv8 pf1 = *(const bv8*)(&pl[wave][lr * 72 + 32 + g * 8]);
    __builtin_amdgcn_s_setprio(1);
#pragma unroll
    for (int n = 0; n < 16; ++n) {
      const unsigned short* vp = vb + (size_t)(n * 16 + lr) * SS + jb;
      bv8 vf0 = *(const bv8*)(vp + g * 8);
      po[n] = __builtin_amdgcn_mfma_f32_16x16x32_bf16(pf0, vf0, po[n], 0, 0, 0);
      bv8 vf1 = *(const bv8*)(vp + 32 + g * 8);
      po[n] = __builtin_amdgcn_mfma_f32_16x16x32_bf16(pf1, vf1, po[n], 0, 0, 0);
    }
    __builtin_amdgcn_s_setprio(0);
    p ^= 1;
  }
#pragma unroll
  for (int off = 1; off < 16; off <<= 1)
#pragma unroll
    for (int r = 0; r < 4; ++r) lsp[r] += __shfl_xor(lsp[r], off, 64);
  float inv[4];
#pragma unroll
  for (int r = 0; r < 4; ++r) inv[r] = 1.0f / lsp[r];
#pragma unroll
  for (int r = 0; r < 4; ++r) {
    size_t row = (size_t)i0 + wave * 16 + g * 4 + r;
    unsigned short* op = att + ((size_t)b * SS + row) * 1024 + h * 256 + lr;
#pragma unroll
    for (int n = 0; n < 16; ++n) op[n * 16] = f2b(po[n][r] * inv[r]);
  }
}

extern "C" void kernel_launch(void* const* d_in, const int* in_sizes, int n_in,
                              void* d_out, int out_size, void* d_ws, size_t ws_size,
                              hipStream_t stream) {
  const float* x    = (const float*)d_in[0];
  // d_in[1] = mask (computed analytically)
  const float* cosp = (const float*)d_in[2];
  const float* sinp = (const float*)d_in[3];
  const float* Wq   = (const float*)d_in[4];
  const float* Wk   = (const float*)d_in[5];
  const float* Wv   = (const float*)d_in[6];
  const float* Wo   = (const float*)d_in[7];
  const float* qsc  = (const float*)d_in[8];
  const float* ksc  = (const float*)d_in[9];
  float* out = (float*)d_out;
  char* ws = (char*)d_ws;

  unsigned short* xb   = (unsigned short*)(ws);               // 8192x640 bf16
  unsigned short* wqkv = (unsigned short*)(ws + 10485760);    // 1536x640 bf16 (W^T)
  unsigned short* wo   = (unsigned short*)(ws + 12451840);    // 640x1024 bf16 (Wo^T)
  unsigned short* qkv  = (unsigned short*)(ws + 13762560);    // 8192x1536 bf16
  unsigned short* qb   = (unsigned short*)(ws + 38928384);    // (B,H,S,D) bf16
  unsigned short* kbuf = (unsigned short*)(ws + 55705600);    // (B,S,D) bf16
  unsigned short* vt   = (unsigned short*)(ws + 59899904);    // (B,D,S) bf16
  unsigned short* attb = (unsigned short*)(ws + 64094208);    // (B,S,H*D) bf16

  k_cast_bf16<<<5120, 256, 0, stream>>>(x, xb, 1310720);
  k_transpose_bf16<float><<<dim3(20, 32), 256, 0, stream>>>(Wq, wqkv, 1024, 640);
  k_transpose_bf16<float><<<dim3(20, 8), 256, 0, stream>>>(Wk, wqkv + 1024 * 640, 256, 640);
  k_transpose_bf16<float><<<dim3(20, 8), 256, 0, stream>>>(Wv, wqkv + 1280 * 640, 256, 640);
  k_transpose_bf16<float><<<dim3(32, 20), 256, 0, stream>>>(Wo, wo, 640, 1024);
  k_gemm<true, 128><<<768, 256, 0, stream>>>(xb, wqkv, qkv, 8192, 1536, 640, 12);
  k_normrope<<<8192, 320, 0, stream>>>(qkv, cosp, sinp, qsc, ksc, qb, kbuf);
  k_transpose_bf16<unsigned short><<<dim3(128, 8), 256, 0, stream>>>(qkv + 1280, vt, 1536, 4096);
  k_transpose_bf16<unsigned short><<<dim3(128, 8), 256, 0, stream>>>(
      qkv + (size_t)4096 * 1536 + 1280, vt + (size_t)256 * 4096, 1536, 4096);
  k_attn<<<512, 256, 0, stream>>>(qb, kbuf, vt, attb);
  k_gemm<false, 64><<<640, 256, 0, stream>>>(attb, wo, out, 8192, 640, 1024, 10);
}

// Round 4
// 140.403 us; speedup vs baseline: 1.2644x; 1.2644x over previous
//
#include <hip/hip_runtime.h>
#include <hip/hip_bf16.h>
#include <stdint.h>

#define BB 2
#define SS 4096
#define EE 640
#define HH 4
#define DD 256
#define WIN 512

typedef __attribute__((ext_vector_type(8))) short bv8;   // 8 bf16 (4 VGPR)
typedef __attribute__((ext_vector_type(4))) float fv4;

__device__ __forceinline__ unsigned short f2b(float f) {
  union { float f; unsigned u; } a; a.f = f;
  unsigned r = a.u + 0x7fffu + ((a.u >> 16) & 1u);   // RNE
  return (unsigned short)(r >> 16);
}
__device__ __forceinline__ float b2f(unsigned short s) {
  union { unsigned u; float f; } a; a.u = ((unsigned)s) << 16;
  return a.f;
}

typedef const __attribute__((address_space(1))) unsigned int* as1u;
typedef __attribute__((address_space(3))) unsigned int* as3u;
__device__ __forceinline__ void gld16(const unsigned short* g, unsigned short* l) {
  // async global->LDS, 16B/lane; LDS dst = wave-uniform base + lane*16
  __builtin_amdgcn_global_load_lds((as1u)(const void*)g, (as3u)(void*)l, 16, 0, 0);
}

// ---------------- f32 -> bf16 cast (x) ----------------
__global__ __launch_bounds__(256) void k_cast_bf16(const float* __restrict__ src,
                                                   unsigned short* __restrict__ dst, int n4) {
  int i = blockIdx.x * 256 + threadIdx.x;
  if (i >= n4) return;
  fv4 v = ((const fv4*)src)[i];
  ushort4 o; o.x = f2b(v.x); o.y = f2b(v.y); o.z = f2b(v.z); o.w = f2b(v.w);
  ((ushort4*)dst)[i] = o;
}

// ---------------- tiled transpose + cast to bf16 (weights only) ------------
template <typename T>
__global__ __launch_bounds__(256) void k_transpose_bf16(const T* __restrict__ src,
    unsigned short* __restrict__ dst, int sstride, int dstride) {
  __shared__ float tile[32][33];
  int r0 = blockIdx.x * 32, c0 = blockIdx.y * 32;
  int t = threadIdx.x;
  int rr = t >> 3, cc = (t & 7) * 4;
  const T* p = src + (size_t)(r0 + rr) * sstride + c0 + cc;
  float v[4];
  if constexpr (sizeof(T) == 4) {
    fv4 x = *(const fv4*)p;
    v[0] = x.x; v[1] = x.y; v[2] = x.z; v[3] = x.w;
  } else {
    ushort4 x = *(const ushort4*)p;
    v[0] = b2f(x.x); v[1] = b2f(x.y); v[2] = b2f(x.z); v[3] = b2f(x.w);
  }
#pragma unroll
  for (int i = 0; i < 4; ++i) tile[cc + i][rr] = v[i];
  __syncthreads();
  ushort4 o;
  o.x = f2b(tile[rr][cc + 0]); o.y = f2b(tile[rr][cc + 1]);
  o.z = f2b(tile[rr][cc + 2]); o.w = f2b(tile[rr][cc + 3]);
  *(ushort4*)(dst + (size_t)(c0 + rr) * dstride + r0 + cc) = o;
}

// ---------------- bf16 GEMM (m97 structure): C(MxN) = A(MxK) * Bt(NxK)^T ----
template <bool OUT_BF16, int BN>
__global__ __launch_bounds__(256) void k_gemm(const unsigned short* __restrict__ A,
    const unsigned short* __restrict__ Bt, void* __restrict__ Cp,
    int M, int N, int K, int nt_n) {
  __shared__ unsigned short la[128 * 32];
  __shared__ unsigned short lb[BN * 32];
  const int bid = blockIdx.x;
  const int gidx = (bid & 7) * (gridDim.x >> 3) + (bid >> 3);
  const int m0 = (gidx / nt_n) * 128, n0 = (gidx % nt_n) * BN;
  const int tid = threadIdx.x, lane = tid & 63, wave = tid >> 6;
  const int g = lane >> 4, lr = lane & 15;
  constexpr int MI = (BN == 128) ? 4 : 2;
  const int wm = (BN == 128) ? (wave >> 1) * 64 : wave * 32;
  const int wn = (BN == 128) ? (wave & 1) * 64 : 0;
  fv4 acc[MI][4] = {};
  const int srow = wave * 32 + (lane >> 2);
  const int sch = (lane & 3) * 8;
  const unsigned short* ga0 = A + (size_t)(m0 + srow) * K + sch;
  unsigned short* lad = la + wave * 1024;
  const int srowb = (BN == 128) ? srow : (wave * 16 + (lane >> 2));
  const unsigned short* gb0 = Bt + (size_t)(n0 + srowb) * K + sch;
  unsigned short* lbd = lb + ((BN == 128) ? wave * 1024 : wave * 512);
  for (int k0 = 0; k0 < K; k0 += 32) {
    __syncthreads();
    gld16(ga0 + k0, lad);
    gld16(ga0 + (size_t)16 * K + k0, lad + 512);
    gld16(gb0 + k0, lbd);
    if constexpr (BN == 128) gld16(gb0 + (size_t)16 * K + k0, lbd + 512);
    __syncthreads();
    bv8 af[MI], bf[4];
#pragma unroll
    for (int mi = 0; mi < MI; ++mi) af[mi] = *(const bv8*)(la + (wm + mi * 16 + lr) * 32 + g * 8);
#pragma unroll
    for (int ni = 0; ni < 4; ++ni) bf[ni] = *(const bv8*)(lb + (wn + ni * 16 + lr) * 32 + g * 8);
    __builtin_amdgcn_s_setprio(1);
#pragma unroll
    for (int mi = 0; mi < MI; ++mi)
#pragma unroll
      for (int ni = 0; ni < 4; ++ni)
        acc[mi][ni] = __builtin_amdgcn_mfma_f32_16x16x32_bf16(af[mi], bf[ni], acc[mi][ni], 0, 0, 0);
    __builtin_amdgcn_s_setprio(0);
  }
#pragma unroll
  for (int mi = 0; mi < MI; ++mi) {
#pragma unroll
    for (int r = 0; r < 4; ++r) {
      size_t row = (size_t)(m0 + wm + mi * 16 + g * 4 + r);
#pragma unroll
      for (int ni = 0; ni < 4; ++ni) {
        int col = n0 + wn + ni * 16 + lr;
        float val = acc[mi][ni][r];
        if constexpr (OUT_BF16)
          ((unsigned short*)Cp)[row * N + col] = f2b(val);
        else
          ((float*)Cp)[row * N + col] = val;
      }
    }
  }
}

// ---------------- rmsnorm + rope (+ SCALING folded into q), bf16 out --------
// qkv row stride is 1280 (q 1024 | k 256); V handled by separate gemm.
__global__ __launch_bounds__(320) void k_normrope(const unsigned short* __restrict__ qkv,
    const float* __restrict__ cosp, const float* __restrict__ sinp,
    const float* __restrict__ qsc, const float* __restrict__ ksc,
    unsigned short* __restrict__ qo, unsigned short* __restrict__ ko) {
  int m = blockIdx.x;
  int b = m >> 12, s = m & 4095;
  int wave = threadIdx.x >> 6, lane = threadIdx.x & 63;
  bool isq = wave < 4;
  const unsigned short* src = qkv + (size_t)m * 1280 + (isq ? wave * 256 : 1024);
  const float* scp = isq ? qsc : ksc;
  int d0 = lane * 4;
  ushort4 raw = *(const ushort4*)(src + d0);
  float x0 = b2f(raw.x), x1 = b2f(raw.y), x2 = b2f(raw.z), x3 = b2f(raw.w);
  float ss = x0 * x0 + x1 * x1 + x2 * x2 + x3 * x3;
#pragma unroll
  for (int off = 1; off < 64; off <<= 1) ss += __shfl_xor(ss, off, 64);
  float rs = rsqrtf(ss * (1.0f / 256.0f) + 1e-6f);
  fv4 sc = *(const fv4*)(scp + d0);
  float n0 = x0 * rs * (1.0f + sc.x);
  float n1 = x1 * rs * (1.0f + sc.y);
  float n2 = x2 * rs * (1.0f + sc.z);
  float n3 = x3 * rs * (1.0f + sc.w);
  float p0 = __shfl_xor(n0, 32, 64);
  float p1 = __shfl_xor(n1, 32, 64);
  float p2 = __shfl_xor(n2, 32, 64);
  float p3 = __shfl_xor(n3, 32, 64);
  float sgn = (lane < 32) ? -1.0f : 1.0f;
  fv4 c4 = *(const fv4*)(cosp + (size_t)s * 256 + d0);
  fv4 s4 = *(const fv4*)(sinp + (size_t)s * 256 + d0);
  float mult = isq ? 0.0625f : 1.0f;
  float o0 = (n0 * c4.x + sgn * p0 * s4.x) * mult;
  float o1 = (n1 * c4.y + sgn * p1 * s4.y) * mult;
  float o2 = (n2 * c4.z + sgn * p2 * s4.z) * mult;
  float o3 = (n3 * c4.w + sgn * p3 * s4.w) * mult;
  ushort4 o; o.x = f2b(o0); o.y = f2b(o1); o.z = f2b(o2); o.w = f2b(o3);
  unsigned short* dst = isq
      ? qo + ((size_t)(b * HH + wave) * SS + s) * 256 + d0
      : ko + ((size_t)b * SS + s) * 256 + d0;
  *(ushort4*)dst = o;
}

// ---------------- flash attention, sliding window 512 ----------------------
// 128 q-rows/block, 4 waves x 32 rows (Mrep=2 -> each K/V fragment read feeds
// 2 MFMAs), K-tile 64, fixed-max softmax (scores bounded by 16: RMSNorm gives
// ||q||=||k||=16, RoPE is norm-preserving, SCALING=1/16).
// K and V double-buffered in LDS via global_load_lds with both-sides XOR
// swizzle (linear dest + pre-swizzled source + swizzled read). One barrier
// per tile; staging latency hidden under the full tile's compute.
__global__ __launch_bounds__(256, 1) void k_attn(const unsigned short* __restrict__ q,
    const unsigned short* __restrict__ kg, const unsigned short* __restrict__ vtg,
    unsigned short* __restrict__ att) {
  __shared__ unsigned short kt[2][64 * 256]; // [key][d] swizzled content (64 KB)
  __shared__ unsigned short vl[2][256 * 64]; // [d][key] swizzled content (64 KB)
  __shared__ unsigned short pl[4][32 * 72];  // per-wave P [qrow][key] (18 KB)
  const int plane = blockIdx.x & 7;          // XCD id == (h,b) plane
  const int h = plane & 3, b = plane >> 2;
  const int i0 = (blockIdx.x >> 3) * 128;
  const int tid = threadIdx.x, wave = tid >> 6, lane = tid & 63;
  const int g = lane >> 4, lr = lane & 15;
  bv8 qf[2][8];
#pragma unroll
  for (int mi = 0; mi < 2; ++mi) {
    const unsigned short* qp =
        q + ((size_t)(b * HH + h) * SS + i0 + wave * 32 + mi * 16 + lr) * 256;
#pragma unroll
    for (int kk = 0; kk < 8; ++kk) qf[mi][kk] = *(const bv8*)(qp + kk * 32 + g * 8);
  }
  fv4 po[2][16] = {};
  float lsp[2][4] = {};
  const int t0 = (i0 >= WIN) ? ((i0 - WIN + 1) >> 6) : 0;
  const int t1 = (i0 + 127) >> 6;
  const unsigned short* kb = kg + (size_t)b * SS * 256;
  const unsigned short* vb = vtg + b * 4096;   // vt is [256][B*S]
  // K tile: 64 rows x 512B. call c: rows wave*16+c*2(+lane>>5), chunk lane&31.
  // LDS slot (row,s) holds global chunk s^(row&7); row&7 == (lane>>5 + c*2)&7... row&7 = ((lane>>5)+2*c)&7? No: row = wave*16+c*2+(lane>>5); wave*16,c*2 even -> row&7 = ((c*2)&7)+(lane>>5) when wave*16%8==0. Source supplies chunk (lane&31)^(row&7).
#define STAGEK(t, pp)                                                         \
  {                                                                           \
    const unsigned short* kbase = kb + (size_t)(t) * 64 * 256;                \
    _Pragma("unroll")                                                         \
    for (int c = 0; c < 8; ++c) {                                             \
      int row_ = wave * 16 + c * 2 + (lane >> 5);                             \
      int sch_ = ((lane & 31) ^ (row_ & 7)) * 8;                              \
      gld16(kbase + (size_t)row_ * 256 + sch_, &kt[pp][(wave * 16 + c * 2) * 256]); \
    }                                                                         \
  }
  // V tile: 256 rows (d) x 128B. call c: rows wave*64+c*8(+lane>>3), chunk lane&7.
#define STAGEV(t, pp)                                                         \
  {                                                                           \
    const unsigned short* vbase = vb + (size_t)(t) * 64;                      \
    _Pragma("unroll")                                                         \
    for (int c = 0; c < 8; ++c) {                                             \
      int d_ = wave * 64 + c * 8 + (lane >> 3);                               \
      int sch_ = ((lane & 7) ^ ((lane >> 3) & 7)) * 8;                        \
      gld16(vbase + (size_t)d_ * (BB * SS) + sch_, &vl[pp][(wave * 64 + c * 8) * 64]); \
    }                                                                         \
  }
  STAGEK(t0, 0);
  STAGEV(t0, 0);
  int p = 0;
  for (int t = t0; t <= t1; ++t) {
    __syncthreads();   // drains all gld_lds (tile t ready); prior tile reads done
    if (t < t1) { STAGEK(t + 1, p ^ 1); STAGEV(t + 1, p ^ 1); }
    fv4 sa[2][4] = {};
    __builtin_amdgcn_s_setprio(1);
#pragma unroll
    for (int n2 = 0; n2 < 4; ++n2) {
      const int row_ = n2 * 16 + lr;
#pragma unroll
      for (int kk = 0; kk < 8; ++kk) {
        bv8 kf = *(const bv8*)(&kt[p][row_ * 256 + (((kk * 4 + g) ^ (row_ & 7)) * 8)]);
        sa[0][n2] = __builtin_amdgcn_mfma_f32_16x16x32_bf16(qf[0][kk], kf, sa[0][n2], 0, 0, 0);
        sa[1][n2] = __builtin_amdgcn_mfma_f32_16x16x32_bf16(qf[1][kk], kf, sa[1][n2], 0, 0, 0);
      }
    }
    __builtin_amdgcn_s_setprio(0);
    const int jb = t * 64;
    const bool need_mask = (jb + 63 > i0) || (i0 + 127 - jb >= WIN);
    if (need_mask) {
#pragma unroll
      for (int mi = 0; mi < 2; ++mi)
#pragma unroll
        for (int n2 = 0; n2 < 4; ++n2) {
          int j = jb + n2 * 16 + lr;
#pragma unroll
          for (int r = 0; r < 4; ++r) {
            int row = i0 + wave * 32 + mi * 16 + g * 4 + r;
            if (j > row || row - j >= WIN) sa[mi][n2][r] = -1e30f;
          }
        }
    }
#pragma unroll
    for (int mi = 0; mi < 2; ++mi)
#pragma unroll
      for (int n2 = 0; n2 < 4; ++n2)
#pragma unroll
        for (int r = 0; r < 4; ++r) {
          float pe = __expf(sa[mi][n2][r] - 16.5f);
          lsp[mi][r] += pe;
          pl[wave][(mi * 16 + g * 4 + r) * 72 + n2 * 16 + lr] = f2b(pe);
        }
    bv8 pfA[2], pfB[2];
#pragma unroll
    for (int mi = 0; mi < 2; ++mi) {
      pfA[mi] = *(const bv8*)(&pl[wave][(mi * 16 + lr) * 72 + g * 8]);
      pfB[mi] = *(const bv8*)(&pl[wave][(mi * 16 + lr) * 72 + 32 + g * 8]);
    }
    __builtin_amdgcn_s_setprio(1);
#pragma unroll
    for (int n = 0; n < 16; ++n) {
      const int vrow = n * 16 + lr;
      bv8 vf0 = *(const bv8*)(&vl[p][vrow * 64 + ((g ^ (vrow & 7)) * 8)]);
      bv8 vf1 = *(const bv8*)(&vl[p][vrow * 64 + (((4 + g) ^ (vrow & 7)) * 8)]);
#pragma unroll
      for (int mi = 0; mi < 2; ++mi) {
        po[mi][n] = __builtin_amdgcn_mfma_f32_16x16x32_bf16(pfA[mi], vf0, po[mi][n], 0, 0, 0);
        po[mi][n] = __builtin_amdgcn_mfma_f32_16x16x32_bf16(pfB[mi], vf1, po[mi][n], 0, 0, 0);
      }
    }
    __builtin_amdgcn_s_setprio(0);
    p ^= 1;
  }
#pragma unroll
  for (int off = 1; off < 16; off <<= 1)
#pragma unroll
    for (int mi = 0; mi < 2; ++mi)
#pragma unroll
      for (int r = 0; r < 4; ++r) lsp[mi][r] += __shfl_xor(lsp[mi][r], off, 64);
#pragma unroll
  for (int mi = 0; mi < 2; ++mi)
#pragma unroll
    for (int r = 0; r < 4; ++r) {
      float inv = 1.0f / lsp[mi][r];
      size_t row = (size_t)i0 + wave * 32 + mi * 16 + g * 4 + r;
      unsigned short* op = att + ((size_t)b * SS + row) * 1024 + h * 256 + lr;
#pragma unroll
      for (int n = 0; n < 16; ++n) op[n * 16] = f2b(po[mi][n][r] * inv);
    }
}

extern "C" void kernel_launch(void* const* d_in, const int* in_sizes, int n_in,
                              void* d_out, int out_size, void* d_ws, size_t ws_size,
                              hipStream_t stream) {
  const float* x    = (const float*)d_in[0];
  // d_in[1] = mask (computed analytically)
  const float* cosp = (const float*)d_in[2];
  const float* sinp = (const float*)d_in[3];
  const float* Wq   = (const float*)d_in[4];
  const float* Wk   = (const float*)d_in[5];
  const float* Wv   = (const float*)d_in[6];
  const float* Wo   = (const float*)d_in[7];
  const float* qsc  = (const float*)d_in[8];
  const float* ksc  = (const float*)d_in[9];
  float* out = (float*)d_out;
  char* ws = (char*)d_ws;

  unsigned short* xb   = (unsigned short*)(ws);               // 8192x640 bf16
  unsigned short* wqkv = (unsigned short*)(ws + 10485760);    // 1536x640 bf16 (Wq^T|Wk^T|Wv^T)
  unsigned short* wo   = (unsigned short*)(ws + 12451840);    // 640x1024 bf16 (Wo^T)
  unsigned short* qkv  = (unsigned short*)(ws + 13762560);    // 8192x1280 bf16 (q|k)
  unsigned short* qb   = (unsigned short*)(ws + 34734080);    // (B,H,S,D) bf16
  unsigned short* kbuf = (unsigned short*)(ws + 51511296);    // (B,S,D) bf16
  unsigned short* vt   = (unsigned short*)(ws + 55705600);    // (D, B*S) bf16
  unsigned short* attb = (unsigned short*)(ws + 59899904);    // (B,S,H*D) bf16

  k_cast_bf16<<<5120, 256, 0, stream>>>(x, xb, 1310720);
  k_transpose_bf16<float><<<dim3(20, 32), 256, 0, stream>>>(Wq, wqkv, 1024, 640);
  k_transpose_bf16<float><<<dim3(20, 8), 256, 0, stream>>>(Wk, wqkv + 1024 * 640, 256, 640);
  k_transpose_bf16<float><<<dim3(20, 8), 256, 0, stream>>>(Wv, wqkv + 1280 * 640, 256, 640);
  k_transpose_bf16<float><<<dim3(32, 20), 256, 0, stream>>>(Wo, wo, 640, 1024);
  k_gemm<true, 128><<<640, 256, 0, stream>>>(xb, wqkv, qkv, 8192, 1280, 640, 10);
  // V^T directly: vt[d][b*S+s] = sum_k Wv^T[d][k] * x[b,s][k]
  k_gemm<true, 128><<<128, 256, 0, stream>>>(wqkv + 1280 * 640, xb, vt, 256, 8192, 640, 64);
  k_normrope<<<8192, 320, 0, stream>>>(qkv, cosp, sinp, qsc, ksc, qb, kbuf);
  k_attn<<<256, 256, 0, stream>>>(qb, kbuf, vt, attb);
  k_gemm<false, 64><<<640, 256, 0, stream>>>(attb, wo, out, 8192, 640, 1024, 10);
}